// Round 8
// baseline (74.486 us; speedup 1.0000x reference)
//
#include <hip/hip_runtime.h>

typedef float f32x4 __attribute__((ext_vector_type(4)));

#define B    32
#define C    256
#define CS   64
#define HW   3136
#define HW4  784
#define EPS  1e-5f

// ---------------- Kernel 1: pool + copy x -> out ----------------
// One block per (b,c) plane. The copy plants out's lines dirty in L3 so
// kernel 2's in-place rescale never touches HBM for its reads.
__global__ __launch_bounds__(256) void se_pool_copy(const float* __restrict__ x,
                                                    float* __restrict__ out,
                                                    float* __restrict__ s) {
    const int bc = blockIdx.x;  // 0..8191
    const f32x4* xp = (const f32x4*)x + (size_t)bc * HW4;
    f32x4*       op = (f32x4*)out + (size_t)bc * HW4;
    float sum = 0.f;
    for (int i = threadIdx.x; i < HW4; i += 256) {
        f32x4 v = xp[i];
        sum += (v.x + v.y) + (v.z + v.w);
        op[i] = v;
    }
    #pragma unroll
    for (int off = 32; off; off >>= 1) sum += __shfl_down(sum, off, 64);
    __shared__ float red[4];
    const int lane = threadIdx.x & 63;
    const int wid  = threadIdx.x >> 6;
    if (lane == 0) red[wid] = sum;
    __syncthreads();
    if (threadIdx.x == 0) {
        float t = (red[0] + red[1]) + (red[2] + red[3]);
        s[bc] = t * (1.0f / (float)HW);
    }
}

// ---------------- Kernel 2: fused MLP + in-place excite ----------------
// Grid: 1024 blocks = (batch b) x (32 groups of 8 channels). Each block
// redundantly computes h[b,:], g for its 8 channels, then rescales its 8
// planes of `out` IN PLACE (read hits L3 lines K1 just wrote).
__global__ __launch_bounds__(256) void se_mlp_scale(
        const float* __restrict__ s,
        const float* __restrict__ w1,
        const float* __restrict__ bn1_gamma, const float* __restrict__ bn1_beta,
        const float* __restrict__ bn1_mean,  const float* __restrict__ bn1_var,
        const float* __restrict__ w2,
        const float* __restrict__ bn2_gamma, const float* __restrict__ bn2_beta,
        const float* __restrict__ bn2_mean,  const float* __restrict__ bn2_var,
        float* __restrict__ out) {
    __shared__ float s_lds[C];
    __shared__ float h_lds[CS];
    __shared__ float g_lds[8];

    const int b  = blockIdx.x >> 5;   // batch row
    const int cg = blockIdx.x & 31;   // channel group (8 channels)
    const int t  = threadIdx.x;

    s_lds[t] = s[b * C + t];
    __syncthreads();

    // h[cs] = ReLU(BN1(dot(s, w1[cs,:]))) — 4 threads per output
    {
        const int cs = t >> 2, j = t & 3;
        const float4* wp = (const float4*)(w1 + cs * C) + j * 16;
        const float*  sp = s_lds + j * 64;
        float p = 0.f;
        #pragma unroll
        for (int k = 0; k < 16; ++k) {
            float4 w = wp[k];
            p += w.x * sp[4*k] + w.y * sp[4*k+1] + w.z * sp[4*k+2] + w.w * sp[4*k+3];
        }
        p += __shfl_xor(p, 1, 64);
        p += __shfl_xor(p, 2, 64);
        if (j == 0) {
            const float sc = bn1_gamma[cs] * rsqrtf(bn1_var[cs] + EPS);
            h_lds[cs] = fmaxf((p - bn1_mean[cs]) * sc + bn1_beta[cs], 0.f);
        }
    }
    __syncthreads();

    // g for this block's 8 channels — threads 0..31, 4 per output
    if (t < 32) {
        const int c = cg * 8 + (t >> 2), j = t & 3;
        const float4* wp = (const float4*)(w2 + c * CS) + j * 4;
        const float*  hp = h_lds + j * 16;
        float a = 0.f;
        #pragma unroll
        for (int k = 0; k < 4; ++k) {
            float4 w = wp[k];
            a += w.x * hp[4*k] + w.y * hp[4*k+1] + w.z * hp[4*k+2] + w.w * hp[4*k+3];
        }
        a += __shfl_xor(a, 1, 64);
        a += __shfl_xor(a, 2, 64);
        if (j == 0) {
            const float sc = bn2_gamma[c] * rsqrtf(bn2_var[c] + EPS);
            float gg = (a - bn2_mean[c]) * sc + bn2_beta[c];
            g_lds[t >> 2] = fminf(fmaxf(gg + 3.f, 0.f), 6.f) * (1.0f / 6.0f);
        }
    }
    __syncthreads();

    // Rescale 8 contiguous planes of out in place: 8*784 = 6272 float4.
    const size_t base4 = (size_t)(b * C + cg * 8) * HW4;
    f32x4* op = (f32x4*)out + base4;
    for (int i = t; i < 8 * HW4; i += 256) {
        const float gv = g_lds[i / HW4];
        f32x4 v = op[i];
        v.x *= gv; v.y *= gv; v.z *= gv; v.w *= gv;
        op[i] = v;
    }
}

extern "C" void kernel_launch(void* const* d_in, const int* in_sizes, int n_in,
                              void* d_out, int out_size, void* d_ws, size_t ws_size,
                              hipStream_t stream) {
    const float* x         = (const float*)d_in[0];
    const float* w1        = (const float*)d_in[1];
    const float* bn1_gamma = (const float*)d_in[2];
    const float* bn1_beta  = (const float*)d_in[3];
    const float* bn1_mean  = (const float*)d_in[4];
    const float* bn1_var   = (const float*)d_in[5];
    const float* w2        = (const float*)d_in[6];
    const float* bn2_gamma = (const float*)d_in[7];
    const float* bn2_beta  = (const float*)d_in[8];
    const float* bn2_mean  = (const float*)d_in[9];
    const float* bn2_var   = (const float*)d_in[10];
    float* out = (float*)d_out;

    float* s = (float*)d_ws;          // 8192 floats

    se_pool_copy<<<B * C, 256, 0, stream>>>(x, out, s);
    se_mlp_scale<<<B * 32, 256, 0, stream>>>(s, w1,
                                             bn1_gamma, bn1_beta, bn1_mean, bn1_var,
                                             w2,
                                             bn2_gamma, bn2_beta, bn2_mean, bn2_var,
                                             out);
}